// Round 1
// baseline (1355.658 us; speedup 1.0000x reference)
//
#include <hip/hip_runtime.h>
#include <math.h>

#define B_DIM 16
#define A_DIM 1024
#define V_DIM 512
#define D_DIM 512
#define NEGV  (-1e30f)

#define TBM 128
#define TBN 128
#define TBK 16

// ---------------------------------------------------------------------------
// NT GEMM: C[M,N] = A[M,K] * B[N,K]^T (+bias), batched via element strides.
// 128x128 tile, BK=16, 256 threads, 8x8 micro-tile per thread.
// ---------------------------------------------------------------------------
__global__ __launch_bounds__(256) void gemm_nt_kernel(
    const float* __restrict__ Ag, const float* __restrict__ Bg,
    const float* __restrict__ bias, float* __restrict__ Cg,
    int M, int N, int K, size_t sA, size_t sB, size_t sC)
{
    __shared__ __align__(16) float As[TBK][TBM + 4];
    __shared__ __align__(16) float Bs[TBK][TBN + 4];

    const float* Ab = Ag + (size_t)blockIdx.z * sA;
    const float* Bb = Bg + (size_t)blockIdx.z * sB;
    float*       Cb = Cg + (size_t)blockIdx.z * sC;

    const int m0 = blockIdx.y * TBM;
    const int n0 = blockIdx.x * TBN;
    const int tid = threadIdx.x;

    const int lr  = tid >> 2;         // 0..63  (row within half-tile)
    const int lk4 = (tid & 3) * 4;    // 0,4,8,12 (k offset, float4 granular)
    const int tx = tid & 15;
    const int ty = tid >> 4;

    const float* aptr0 = Ab + (size_t)(m0 + lr)      * K + lk4;
    const float* aptr1 = Ab + (size_t)(m0 + lr + 64) * K + lk4;
    const float* bptr0 = Bb + (size_t)(n0 + lr)      * K + lk4;
    const float* bptr1 = Bb + (size_t)(n0 + lr + 64) * K + lk4;

    float acc[8][8];
    #pragma unroll
    for (int i = 0; i < 8; ++i)
        #pragma unroll
        for (int j = 0; j < 8; ++j) acc[i][j] = 0.f;

    for (int k0 = 0; k0 < K; k0 += TBK) {
        float4 a0 = *(const float4*)(aptr0 + k0);
        float4 a1 = *(const float4*)(aptr1 + k0);
        float4 b0 = *(const float4*)(bptr0 + k0);
        float4 b1 = *(const float4*)(bptr1 + k0);
        __syncthreads();
        As[lk4+0][lr]    = a0.x; As[lk4+1][lr]    = a0.y; As[lk4+2][lr]    = a0.z; As[lk4+3][lr]    = a0.w;
        As[lk4+0][lr+64] = a1.x; As[lk4+1][lr+64] = a1.y; As[lk4+2][lr+64] = a1.z; As[lk4+3][lr+64] = a1.w;
        Bs[lk4+0][lr]    = b0.x; Bs[lk4+1][lr]    = b0.y; Bs[lk4+2][lr]    = b0.z; Bs[lk4+3][lr]    = b0.w;
        Bs[lk4+0][lr+64] = b1.x; Bs[lk4+1][lr+64] = b1.y; Bs[lk4+2][lr+64] = b1.z; Bs[lk4+3][lr+64] = b1.w;
        __syncthreads();
        #pragma unroll
        for (int kk = 0; kk < TBK; ++kk) {
            float4 av0 = *(const float4*)&As[kk][ty*8];
            float4 av1 = *(const float4*)&As[kk][ty*8+4];
            float4 bv0 = *(const float4*)&Bs[kk][tx*8];
            float4 bv1 = *(const float4*)&Bs[kk][tx*8+4];
            float a[8] = {av0.x, av0.y, av0.z, av0.w, av1.x, av1.y, av1.z, av1.w};
            float b[8] = {bv0.x, bv0.y, bv0.z, bv0.w, bv1.x, bv1.y, bv1.z, bv1.w};
            #pragma unroll
            for (int i = 0; i < 8; ++i)
                #pragma unroll
                for (int j = 0; j < 8; ++j)
                    acc[i][j] = fmaf(a[i], b[j], acc[i][j]);
        }
    }

    float bv[8];
    #pragma unroll
    for (int j = 0; j < 8; ++j) bv[j] = bias ? bias[n0 + tx*8 + j] : 0.f;
    #pragma unroll
    for (int i = 0; i < 8; ++i) {
        float* crow = Cb + (size_t)(m0 + ty*8 + i) * N + n0 + tx*8;
        float4 o0 = make_float4(acc[i][0]+bv[0], acc[i][1]+bv[1], acc[i][2]+bv[2], acc[i][3]+bv[3]);
        float4 o1 = make_float4(acc[i][4]+bv[4], acc[i][5]+bv[5], acc[i][6]+bv[6], acc[i][7]+bv[7]);
        *(float4*)(crow)     = o0;
        *(float4*)(crow + 4) = o1;
    }
}

// ---------------------------------------------------------------------------
// Row L2-normalize in place: x[r,:] /= max(||x[r,:]||, 1e-12). One wave/row.
// ---------------------------------------------------------------------------
__global__ __launch_bounds__(256) void rownorm_kernel(float* __restrict__ x)
{
    const int wave = threadIdx.x >> 6;
    const int lane = threadIdx.x & 63;
    const size_t r = (size_t)blockIdx.x * 4 + wave;
    float* p = x + r * D_DIM;
    float4 u = *(float4*)(p + lane*4);
    float4 w = *(float4*)(p + 256 + lane*4);
    float ss = u.x*u.x + u.y*u.y + u.z*u.z + u.w*u.w
             + w.x*w.x + w.y*w.y + w.z*w.z + w.w*w.w;
    #pragma unroll
    for (int m = 1; m < 64; m <<= 1) ss += __shfl_xor(ss, m, 64);
    const float inv = 1.0f / fmaxf(sqrtf(ss), 1e-12f);
    u.x*=inv; u.y*=inv; u.z*=inv; u.w*=inv;
    w.x*=inv; w.y*=inv; w.z*=inv; w.w*=inv;
    *(float4*)(p + lane*4)       = u;
    *(float4*)(p + 256 + lane*4) = w;
}

// ---------------------------------------------------------------------------
// Softmax row stats over sim rows: rmax[r], rinv[r] = 1/sum(exp(s-max)).
// ---------------------------------------------------------------------------
__global__ __launch_bounds__(256) void rowstat_kernel(
    const float* __restrict__ sim, float* __restrict__ rmax, float* __restrict__ rinv)
{
    const int wave = threadIdx.x >> 6;
    const int lane = threadIdx.x & 63;
    const size_t r = (size_t)blockIdx.x * 4 + wave;
    const float* p = sim + r * V_DIM;
    float4 u = *(const float4*)(p + lane*4);
    float4 w = *(const float4*)(p + 256 + lane*4);
    float m = fmaxf(fmaxf(fmaxf(u.x,u.y), fmaxf(u.z,u.w)),
                    fmaxf(fmaxf(w.x,w.y), fmaxf(w.z,w.w)));
    #pragma unroll
    for (int s = 1; s < 64; s <<= 1) m = fmaxf(m, __shfl_xor(m, s, 64));
    float e = __expf(u.x-m)+__expf(u.y-m)+__expf(u.z-m)+__expf(u.w-m)
            + __expf(w.x-m)+__expf(w.y-m)+__expf(w.z-m)+__expf(w.w-m);
    #pragma unroll
    for (int s = 1; s < 64; s <<= 1) e += __shfl_xor(e, s, 64);
    if (lane == 0) { rmax[r] = m; rinv[r] = 1.0f / e; }
}

// ---------------------------------------------------------------------------
// PV GEMM (NN): out[b] = softmax(sim[b]) @ video[b]. P computed on the fly
// from sim + row stats. Same 128x128x16 tiling.
// ---------------------------------------------------------------------------
__global__ __launch_bounds__(256) void gemm_pv_kernel(
    const float* __restrict__ sim, const float* __restrict__ rmax,
    const float* __restrict__ rinv, const float* __restrict__ video,
    float* __restrict__ out)
{
    __shared__ __align__(16) float As[TBK][TBM + 4];
    __shared__ __align__(16) float Bs[TBK][TBN + 4];

    const int b = blockIdx.z;
    const float* Sb = sim   + (size_t)b * A_DIM * V_DIM;
    const float* Vb = video + (size_t)b * V_DIM * D_DIM;
    float*       Ob = out   + (size_t)b * A_DIM * D_DIM;

    const int m0 = blockIdx.y * TBM;
    const int n0 = blockIdx.x * TBN;
    const int tid = threadIdx.x;

    const int lr  = tid >> 2;        // 0..63
    const int lk4 = (tid & 3) * 4;   // 0,4,8,12
    const int bkk = tid >> 4;        // 0..15 (k row for B tile)
    const int bn4 = (tid & 15) * 4;  // 0..60 (n offset, float4)
    const int tx = tid & 15;
    const int ty = tid >> 4;

    const float rm0 = rmax[(size_t)b*A_DIM + m0 + lr];
    const float ri0 = rinv[(size_t)b*A_DIM + m0 + lr];
    const float rm1 = rmax[(size_t)b*A_DIM + m0 + lr + 64];
    const float ri1 = rinv[(size_t)b*A_DIM + m0 + lr + 64];

    const float* sptr0 = Sb + (size_t)(m0 + lr)      * V_DIM + lk4;
    const float* sptr1 = Sb + (size_t)(m0 + lr + 64) * V_DIM + lk4;

    float acc[8][8];
    #pragma unroll
    for (int i = 0; i < 8; ++i)
        #pragma unroll
        for (int j = 0; j < 8; ++j) acc[i][j] = 0.f;

    const float L2E = 1.44269504f;
    for (int k0 = 0; k0 < V_DIM; k0 += TBK) {
        float4 s0 = *(const float4*)(sptr0 + k0);
        float4 s1 = *(const float4*)(sptr1 + k0);
        float4 v0 = *(const float4*)(Vb + (size_t)(k0 + bkk) * D_DIM + n0 + bn4);
        float4 v1 = *(const float4*)(Vb + (size_t)(k0 + bkk) * D_DIM + n0 + bn4 + 64);
        __syncthreads();
        As[lk4+0][lr]    = exp2f((s0.x-rm0)*L2E)*ri0;
        As[lk4+1][lr]    = exp2f((s0.y-rm0)*L2E)*ri0;
        As[lk4+2][lr]    = exp2f((s0.z-rm0)*L2E)*ri0;
        As[lk4+3][lr]    = exp2f((s0.w-rm0)*L2E)*ri0;
        As[lk4+0][lr+64] = exp2f((s1.x-rm1)*L2E)*ri1;
        As[lk4+1][lr+64] = exp2f((s1.y-rm1)*L2E)*ri1;
        As[lk4+2][lr+64] = exp2f((s1.z-rm1)*L2E)*ri1;
        As[lk4+3][lr+64] = exp2f((s1.w-rm1)*L2E)*ri1;
        *(float4*)&Bs[bkk][bn4]      = v0;
        *(float4*)&Bs[bkk][bn4+64]   = v1;
        __syncthreads();
        #pragma unroll
        for (int kk = 0; kk < TBK; ++kk) {
            float4 av0 = *(const float4*)&As[kk][ty*8];
            float4 av1 = *(const float4*)&As[kk][ty*8+4];
            float4 bv0 = *(const float4*)&Bs[kk][tx*8];
            float4 bv1 = *(const float4*)&Bs[kk][tx*8+4];
            float a[8] = {av0.x, av0.y, av0.z, av0.w, av1.x, av1.y, av1.z, av1.w};
            float bb[8] = {bv0.x, bv0.y, bv0.z, bv0.w, bv1.x, bv1.y, bv1.z, bv1.w};
            #pragma unroll
            for (int i = 0; i < 8; ++i)
                #pragma unroll
                for (int j = 0; j < 8; ++j)
                    acc[i][j] = fmaf(a[i], bb[j], acc[i][j]);
        }
    }

    #pragma unroll
    for (int i = 0; i < 8; ++i) {
        float* crow = Ob + (size_t)(m0 + ty*8 + i) * D_DIM + n0 + tx*8;
        float4 o0 = make_float4(acc[i][0], acc[i][1], acc[i][2], acc[i][3]);
        float4 o1 = make_float4(acc[i][4], acc[i][5], acc[i][6], acc[i][7]);
        *(float4*)(crow)     = o0;
        *(float4*)(crow + 4) = o1;
    }
}

// ---------------------------------------------------------------------------
// DTW: anti-diagonal wavefront. One block (512 threads) per batch.
// dp[i][j] = sim[i-1][j-1] + max(dp[i-1][j], dp[i][j-1], dp[i-1][j-1]).
// Three rotating diagonal buffers in LDS; untouched cells stay NEG.
// ---------------------------------------------------------------------------
__global__ __launch_bounds__(512) void dtw_kernel(
    const float* __restrict__ sim, float* __restrict__ score)
{
    const int b = blockIdx.x;
    const float* S = sim + (size_t)b * A_DIM * V_DIM;
    __shared__ float buf[3][V_DIM + 1];
    const int t = threadIdx.x;   // 0..511
    const int j = t + 1;         // column 1..512
    for (int idx = t; idx <= V_DIM; idx += 512) {
        buf[0][idx] = NEGV; buf[1][idx] = NEGV; buf[2][idx] = NEGV;
    }
    __syncthreads();
    for (int d = 2; d <= A_DIM + V_DIM; ++d) {
        const int i = d - j;
        float* dpw       = buf[d % 3];
        const float* dp1 = buf[(d + 2) % 3];   // diagonal d-1
        const float* dp2 = buf[(d + 1) % 3];   // diagonal d-2
        if (i >= 1 && i <= A_DIM) {
            float up   = dp1[j];
            float left = dp1[j - 1];
            float diag = (i == 1 && j == 1) ? 0.0f : dp2[j - 1];
            float val = S[(size_t)(i - 1) * V_DIM + (j - 1)]
                      + fmaxf(fmaxf(up, left), diag);
            dpw[j] = val;
        }
        __syncthreads();
    }
    if (t == 0) score[b] = buf[(A_DIM + V_DIM) % 3][V_DIM];
}

// ---------------------------------------------------------------------------
extern "C" void kernel_launch(void* const* d_in, const int* in_sizes, int n_in,
                              void* d_out, int out_size, void* d_ws, size_t ws_size,
                              hipStream_t stream)
{
    const float* audio = (const float*)d_in[0];   // [16,1024,512]
    const float* video = (const float*)d_in[1];   // [16, 512,512]
    const float* W     = (const float*)d_in[2];   // [512,512]
    const float* bias  = (const float*)d_in[3];   // [512]

    float* out_aligned = (float*)d_out;                                   // [16,1024,512]
    float* out_score   = (float*)d_out + (size_t)B_DIM * A_DIM * D_DIM;   // [16]

    float* ws   = (float*)d_ws;
    float* a_n  = ws;                                        // 16384 x 512
    float* v_n  = a_n  + (size_t)B_DIM * A_DIM * D_DIM;      //  8192 x 512 (contiguous after a_n)
    float* sim  = v_n  + (size_t)B_DIM * V_DIM * D_DIM;      // 16 x 1024 x 512
    float* rmax = sim  + (size_t)B_DIM * A_DIM * V_DIM;      // 16384
    float* rinv = rmax + (size_t)B_DIM * A_DIM;              // 16384

    // 1) projections: X @ W^T + b
    gemm_nt_kernel<<<dim3(D_DIM/TBN, (B_DIM*A_DIM)/TBM, 1), dim3(256), 0, stream>>>(
        audio, W, bias, a_n, B_DIM*A_DIM, D_DIM, D_DIM, 0, 0, 0);
    gemm_nt_kernel<<<dim3(D_DIM/TBN, (B_DIM*V_DIM)/TBM, 1), dim3(256), 0, stream>>>(
        video, W, bias, v_n, B_DIM*V_DIM, D_DIM, D_DIM, 0, 0, 0);

    // 2) L2-normalize all 24576 projected rows (a_n and v_n are contiguous)
    rownorm_kernel<<<dim3((B_DIM*(A_DIM+V_DIM))/4), dim3(256), 0, stream>>>(a_n);

    // 3) sim[b] = a_n[b] @ v_n[b]^T   (batched NT)
    gemm_nt_kernel<<<dim3(V_DIM/TBN, A_DIM/TBM, B_DIM), dim3(256), 0, stream>>>(
        a_n, v_n, nullptr, sim, A_DIM, V_DIM, D_DIM,
        (size_t)A_DIM*D_DIM, (size_t)V_DIM*D_DIM, (size_t)A_DIM*V_DIM);

    // 4) softmax row stats
    rowstat_kernel<<<dim3((B_DIM*A_DIM)/4), dim3(256), 0, stream>>>(sim, rmax, rinv);

    // 5) aligned = softmax(sim) @ video
    gemm_pv_kernel<<<dim3(D_DIM/TBN, A_DIM/TBM, B_DIM), dim3(256), 0, stream>>>(
        sim, rmax, rinv, video, out_aligned);

    // 6) DTW alignment score
    dtw_kernel<<<dim3(B_DIM), dim3(V_DIM), 0, stream>>>(sim, out_score);
}

// Round 2
// 843.534 us; speedup vs baseline: 1.6071x; 1.6071x over previous
//
#include <hip/hip_runtime.h>
#include <math.h>

#define B_DIM 16
#define A_DIM 1024
#define V_DIM 512
#define D_DIM 512
#define NEGV  (-1e30f)

#define TBM 128
#define TBN 128
#define TBK 16

// ---------------------------------------------------------------------------
// NT GEMM: C[M,N] = A[M,K] * B[N,K]^T (+bias), batched via element strides.
// 128x128 tile, BK=16, 256 threads, 8x8 micro-tile per thread.
// ---------------------------------------------------------------------------
__global__ __launch_bounds__(256) void gemm_nt_kernel(
    const float* __restrict__ Ag, const float* __restrict__ Bg,
    const float* __restrict__ bias, float* __restrict__ Cg,
    int M, int N, int K, size_t sA, size_t sB, size_t sC)
{
    __shared__ __align__(16) float As[TBK][TBM + 4];
    __shared__ __align__(16) float Bs[TBK][TBN + 4];

    const float* Ab = Ag + (size_t)blockIdx.z * sA;
    const float* Bb = Bg + (size_t)blockIdx.z * sB;
    float*       Cb = Cg + (size_t)blockIdx.z * sC;

    const int m0 = blockIdx.y * TBM;
    const int n0 = blockIdx.x * TBN;
    const int tid = threadIdx.x;

    const int lr  = tid >> 2;         // 0..63  (row within half-tile)
    const int lk4 = (tid & 3) * 4;    // 0,4,8,12 (k offset, float4 granular)
    const int tx = tid & 15;
    const int ty = tid >> 4;

    const float* aptr0 = Ab + (size_t)(m0 + lr)      * K + lk4;
    const float* aptr1 = Ab + (size_t)(m0 + lr + 64) * K + lk4;
    const float* bptr0 = Bb + (size_t)(n0 + lr)      * K + lk4;
    const float* bptr1 = Bb + (size_t)(n0 + lr + 64) * K + lk4;

    float acc[8][8];
    #pragma unroll
    for (int i = 0; i < 8; ++i)
        #pragma unroll
        for (int j = 0; j < 8; ++j) acc[i][j] = 0.f;

    for (int k0 = 0; k0 < K; k0 += TBK) {
        float4 a0 = *(const float4*)(aptr0 + k0);
        float4 a1 = *(const float4*)(aptr1 + k0);
        float4 b0 = *(const float4*)(bptr0 + k0);
        float4 b1 = *(const float4*)(bptr1 + k0);
        __syncthreads();
        As[lk4+0][lr]    = a0.x; As[lk4+1][lr]    = a0.y; As[lk4+2][lr]    = a0.z; As[lk4+3][lr]    = a0.w;
        As[lk4+0][lr+64] = a1.x; As[lk4+1][lr+64] = a1.y; As[lk4+2][lr+64] = a1.z; As[lk4+3][lr+64] = a1.w;
        Bs[lk4+0][lr]    = b0.x; Bs[lk4+1][lr]    = b0.y; Bs[lk4+2][lr]    = b0.z; Bs[lk4+3][lr]    = b0.w;
        Bs[lk4+0][lr+64] = b1.x; Bs[lk4+1][lr+64] = b1.y; Bs[lk4+2][lr+64] = b1.z; Bs[lk4+3][lr+64] = b1.w;
        __syncthreads();
        #pragma unroll
        for (int kk = 0; kk < TBK; ++kk) {
            float4 av0 = *(const float4*)&As[kk][ty*8];
            float4 av1 = *(const float4*)&As[kk][ty*8+4];
            float4 bv0 = *(const float4*)&Bs[kk][tx*8];
            float4 bv1 = *(const float4*)&Bs[kk][tx*8+4];
            float a[8] = {av0.x, av0.y, av0.z, av0.w, av1.x, av1.y, av1.z, av1.w};
            float b[8] = {bv0.x, bv0.y, bv0.z, bv0.w, bv1.x, bv1.y, bv1.z, bv1.w};
            #pragma unroll
            for (int i = 0; i < 8; ++i)
                #pragma unroll
                for (int j = 0; j < 8; ++j)
                    acc[i][j] = fmaf(a[i], b[j], acc[i][j]);
        }
    }

    float bv[8];
    #pragma unroll
    for (int j = 0; j < 8; ++j) bv[j] = bias ? bias[n0 + tx*8 + j] : 0.f;
    #pragma unroll
    for (int i = 0; i < 8; ++i) {
        float* crow = Cb + (size_t)(m0 + ty*8 + i) * N + n0 + tx*8;
        float4 o0 = make_float4(acc[i][0]+bv[0], acc[i][1]+bv[1], acc[i][2]+bv[2], acc[i][3]+bv[3]);
        float4 o1 = make_float4(acc[i][4]+bv[4], acc[i][5]+bv[5], acc[i][6]+bv[6], acc[i][7]+bv[7]);
        *(float4*)(crow)     = o0;
        *(float4*)(crow + 4) = o1;
    }
}

// ---------------------------------------------------------------------------
// Row L2-normalize in place: x[r,:] /= max(||x[r,:]||, 1e-12). One wave/row.
// ---------------------------------------------------------------------------
__global__ __launch_bounds__(256) void rownorm_kernel(float* __restrict__ x)
{
    const int wave = threadIdx.x >> 6;
    const int lane = threadIdx.x & 63;
    const size_t r = (size_t)blockIdx.x * 4 + wave;
    float* p = x + r * D_DIM;
    float4 u = *(float4*)(p + lane*4);
    float4 w = *(float4*)(p + 256 + lane*4);
    float ss = u.x*u.x + u.y*u.y + u.z*u.z + u.w*u.w
             + w.x*w.x + w.y*w.y + w.z*w.z + w.w*w.w;
    #pragma unroll
    for (int m = 1; m < 64; m <<= 1) ss += __shfl_xor(ss, m, 64);
    const float inv = 1.0f / fmaxf(sqrtf(ss), 1e-12f);
    u.x*=inv; u.y*=inv; u.z*=inv; u.w*=inv;
    w.x*=inv; w.y*=inv; w.z*=inv; w.w*=inv;
    *(float4*)(p + lane*4)       = u;
    *(float4*)(p + 256 + lane*4) = w;
}

// ---------------------------------------------------------------------------
// Softmax row stats over sim rows: rmax[r], rinv[r] = 1/sum(exp(s-max)).
// ---------------------------------------------------------------------------
__global__ __launch_bounds__(256) void rowstat_kernel(
    const float* __restrict__ sim, float* __restrict__ rmax, float* __restrict__ rinv)
{
    const int wave = threadIdx.x >> 6;
    const int lane = threadIdx.x & 63;
    const size_t r = (size_t)blockIdx.x * 4 + wave;
    const float* p = sim + r * V_DIM;
    float4 u = *(const float4*)(p + lane*4);
    float4 w = *(const float4*)(p + 256 + lane*4);
    float m = fmaxf(fmaxf(fmaxf(u.x,u.y), fmaxf(u.z,u.w)),
                    fmaxf(fmaxf(w.x,w.y), fmaxf(w.z,w.w)));
    #pragma unroll
    for (int s = 1; s < 64; s <<= 1) m = fmaxf(m, __shfl_xor(m, s, 64));
    float e = __expf(u.x-m)+__expf(u.y-m)+__expf(u.z-m)+__expf(u.w-m)
            + __expf(w.x-m)+__expf(w.y-m)+__expf(w.z-m)+__expf(w.w-m);
    #pragma unroll
    for (int s = 1; s < 64; s <<= 1) e += __shfl_xor(e, s, 64);
    if (lane == 0) { rmax[r] = m; rinv[r] = 1.0f / e; }
}

// ---------------------------------------------------------------------------
// PV GEMM (NN): out[b] = softmax(sim[b]) @ video[b]. P computed on the fly
// from sim + row stats. Same 128x128x16 tiling.
// ---------------------------------------------------------------------------
__global__ __launch_bounds__(256) void gemm_pv_kernel(
    const float* __restrict__ sim, const float* __restrict__ rmax,
    const float* __restrict__ rinv, const float* __restrict__ video,
    float* __restrict__ out)
{
    __shared__ __align__(16) float As[TBK][TBM + 4];
    __shared__ __align__(16) float Bs[TBK][TBN + 4];

    const int b = blockIdx.z;
    const float* Sb = sim   + (size_t)b * A_DIM * V_DIM;
    const float* Vb = video + (size_t)b * V_DIM * D_DIM;
    float*       Ob = out   + (size_t)b * A_DIM * D_DIM;

    const int m0 = blockIdx.y * TBM;
    const int n0 = blockIdx.x * TBN;
    const int tid = threadIdx.x;

    const int lr  = tid >> 2;        // 0..63
    const int lk4 = (tid & 3) * 4;   // 0,4,8,12
    const int bkk = tid >> 4;        // 0..15 (k row for B tile)
    const int bn4 = (tid & 15) * 4;  // 0..60 (n offset, float4)
    const int tx = tid & 15;
    const int ty = tid >> 4;

    const float rm0 = rmax[(size_t)b*A_DIM + m0 + lr];
    const float ri0 = rinv[(size_t)b*A_DIM + m0 + lr];
    const float rm1 = rmax[(size_t)b*A_DIM + m0 + lr + 64];
    const float ri1 = rinv[(size_t)b*A_DIM + m0 + lr + 64];

    const float* sptr0 = Sb + (size_t)(m0 + lr)      * V_DIM + lk4;
    const float* sptr1 = Sb + (size_t)(m0 + lr + 64) * V_DIM + lk4;

    float acc[8][8];
    #pragma unroll
    for (int i = 0; i < 8; ++i)
        #pragma unroll
        for (int j = 0; j < 8; ++j) acc[i][j] = 0.f;

    const float L2E = 1.44269504f;
    for (int k0 = 0; k0 < V_DIM; k0 += TBK) {
        float4 s0 = *(const float4*)(sptr0 + k0);
        float4 s1 = *(const float4*)(sptr1 + k0);
        float4 v0 = *(const float4*)(Vb + (size_t)(k0 + bkk) * D_DIM + n0 + bn4);
        float4 v1 = *(const float4*)(Vb + (size_t)(k0 + bkk) * D_DIM + n0 + bn4 + 64);
        __syncthreads();
        As[lk4+0][lr]    = exp2f((s0.x-rm0)*L2E)*ri0;
        As[lk4+1][lr]    = exp2f((s0.y-rm0)*L2E)*ri0;
        As[lk4+2][lr]    = exp2f((s0.z-rm0)*L2E)*ri0;
        As[lk4+3][lr]    = exp2f((s0.w-rm0)*L2E)*ri0;
        As[lk4+0][lr+64] = exp2f((s1.x-rm1)*L2E)*ri1;
        As[lk4+1][lr+64] = exp2f((s1.y-rm1)*L2E)*ri1;
        As[lk4+2][lr+64] = exp2f((s1.z-rm1)*L2E)*ri1;
        As[lk4+3][lr+64] = exp2f((s1.w-rm1)*L2E)*ri1;
        *(float4*)&Bs[bkk][bn4]      = v0;
        *(float4*)&Bs[bkk][bn4+64]   = v1;
        __syncthreads();
        #pragma unroll
        for (int kk = 0; kk < TBK; ++kk) {
            float4 av0 = *(const float4*)&As[kk][ty*8];
            float4 av1 = *(const float4*)&As[kk][ty*8+4];
            float4 bv0 = *(const float4*)&Bs[kk][tx*8];
            float4 bv1 = *(const float4*)&Bs[kk][tx*8+4];
            float a[8] = {av0.x, av0.y, av0.z, av0.w, av1.x, av1.y, av1.z, av1.w};
            float bb[8] = {bv0.x, bv0.y, bv0.z, bv0.w, bv1.x, bv1.y, bv1.z, bv1.w};
            #pragma unroll
            for (int i = 0; i < 8; ++i)
                #pragma unroll
                for (int j = 0; j < 8; ++j)
                    acc[i][j] = fmaf(a[i], bb[j], acc[i][j]);
        }
    }

    #pragma unroll
    for (int i = 0; i < 8; ++i) {
        float* crow = Ob + (size_t)(m0 + ty*8 + i) * D_DIM + n0 + tx*8;
        float4 o0 = make_float4(acc[i][0], acc[i][1], acc[i][2], acc[i][3]);
        float4 o1 = make_float4(acc[i][4], acc[i][5], acc[i][6], acc[i][7]);
        *(float4*)(crow)     = o0;
        *(float4*)(crow + 4) = o1;
    }
}

// ---------------------------------------------------------------------------
// DTW via (max,+) row scans. One wave (64 lanes) per batch, no LDS/barriers.
//
// Row recurrence dp[j] = c_j + max(m_j, dp[j-1]), m_j = max(up_j, diag_j),
// rewritten with prefix sums P_j = sum_{l<=j} c_l:
//   dp_j = P_j + max_{k<=j} (m_k - P_{k-1})     (prefix-max of q_k).
// Lane l owns columns j = 8l+1 .. 8l+8 (contiguous). In-lane serial scans +
// 6-step wave64 DPP scans (row_shr 1/2/4/8, row_bcast 15/31).
// ---------------------------------------------------------------------------
template <int CTRL, int RMASK>
__device__ __forceinline__ float fdpp(float oldv, float src) {
    int r = __builtin_amdgcn_update_dpp(
        __float_as_int(oldv), __float_as_int(src), CTRL, RMASK, 0xF, false);
    return __int_as_float(r);
}

__device__ __forceinline__ float wave_incl_add(float x) {
    x += fdpp<0x111, 0xF>(0.f, x);   // row_shr:1
    x += fdpp<0x112, 0xF>(0.f, x);   // row_shr:2
    x += fdpp<0x114, 0xF>(0.f, x);   // row_shr:4
    x += fdpp<0x118, 0xF>(0.f, x);   // row_shr:8
    x += fdpp<0x142, 0xA>(0.f, x);   // row_bcast:15 -> rows 1,3
    x += fdpp<0x143, 0xC>(0.f, x);   // row_bcast:31 -> rows 2,3
    return x;
}

__device__ __forceinline__ float wave_incl_max(float x) {
    x = fmaxf(x, fdpp<0x111, 0xF>(NEGV, x));
    x = fmaxf(x, fdpp<0x112, 0xF>(NEGV, x));
    x = fmaxf(x, fdpp<0x114, 0xF>(NEGV, x));
    x = fmaxf(x, fdpp<0x118, 0xF>(NEGV, x));
    x = fmaxf(x, fdpp<0x142, 0xA>(NEGV, x));
    x = fmaxf(x, fdpp<0x143, 0xC>(NEGV, x));
    return x;
}

__device__ __forceinline__ void dtw_row(const float c[8], float dp[8], float bnd)
{
    // in-lane inclusive prefix sum of this lane's 8 costs
    float ps[8];
    ps[0] = c[0];
    #pragma unroll
    for (int k = 1; k < 8; ++k) ps[k] = ps[k-1] + c[k];
    // wave-exclusive sum of lane totals -> global P
    float Pexcl = fdpp<0x138, 0xF>(0.0f, wave_incl_add(ps[7]));   // wave_shr:1
    float Pk[8];
    #pragma unroll
    for (int k = 0; k < 8; ++k) Pk[k] = Pexcl + ps[k];
    // previous row shifted by one column (lane boundary via wave_shr:1)
    float prevlast = fdpp<0x138, 0xF>(bnd, dp[7]);
    // q_k = max(up, diag) - P_{k-1}
    float q[8];
    q[0] = fmaxf(dp[0], prevlast) - Pexcl;
    #pragma unroll
    for (int k = 1; k < 8; ++k) q[k] = fmaxf(dp[k], dp[k-1]) - Pk[k-1];
    // in-lane inclusive max scan
    float qs[8];
    qs[0] = q[0];
    #pragma unroll
    for (int k = 1; k < 8; ++k) qs[k] = fmaxf(qs[k-1], q[k]);
    // wave-exclusive max of lane maxima
    float Qexcl = fdpp<0x138, 0xF>(NEGV, wave_incl_max(qs[7]));
    // dp_j = P_j + prefixmax(q)_j
    #pragma unroll
    for (int k = 0; k < 8; ++k) dp[k] = Pk[k] + fmaxf(Qexcl, qs[k]);
}

__global__ __launch_bounds__(64) void dtw_scan_kernel(
    const float* __restrict__ sim, float* __restrict__ score)
{
    const int b = blockIdx.x;
    const int lane = threadIdx.x;
    const float* S = sim + (size_t)b * A_DIM * V_DIM + lane * 8;

    float dp[8];
    #pragma unroll
    for (int k = 0; k < 8; ++k) dp[k] = NEGV;

    // 2-row-deep load pipeline
    float4 a0 = *(const float4*)(S);
    float4 b0 = *(const float4*)(S + 4);
    float4 a1 = *(const float4*)(S + V_DIM);
    float4 b1 = *(const float4*)(S + V_DIM + 4);

    for (int i = 1; i <= A_DIM; i += 2) {
        float c[8] = {a0.x,a0.y,a0.z,a0.w,b0.x,b0.y,b0.z,b0.w};
        if (i + 2 <= A_DIM) {
            a0 = *(const float4*)(S + (size_t)(i+1) * V_DIM);
            b0 = *(const float4*)(S + (size_t)(i+1) * V_DIM + 4);
        }
        dtw_row(c, dp, (i == 1) ? 0.0f : NEGV);
        float c2[8] = {a1.x,a1.y,a1.z,a1.w,b1.x,b1.y,b1.z,b1.w};
        if (i + 3 <= A_DIM) {
            a1 = *(const float4*)(S + (size_t)(i+2) * V_DIM);
            b1 = *(const float4*)(S + (size_t)(i+2) * V_DIM + 4);
        }
        dtw_row(c2, dp, NEGV);
    }
    if (lane == 63) score[b] = dp[7];   // dp[A][V]
}

// ---------------------------------------------------------------------------
extern "C" void kernel_launch(void* const* d_in, const int* in_sizes, int n_in,
                              void* d_out, int out_size, void* d_ws, size_t ws_size,
                              hipStream_t stream)
{
    const float* audio = (const float*)d_in[0];   // [16,1024,512]
    const float* video = (const float*)d_in[1];   // [16, 512,512]
    const float* W     = (const float*)d_in[2];   // [512,512]
    const float* bias  = (const float*)d_in[3];   // [512]

    float* out_aligned = (float*)d_out;                                   // [16,1024,512]
    float* out_score   = (float*)d_out + (size_t)B_DIM * A_DIM * D_DIM;   // [16]

    float* ws   = (float*)d_ws;
    float* a_n  = ws;                                        // 16384 x 512
    float* v_n  = a_n  + (size_t)B_DIM * A_DIM * D_DIM;      //  8192 x 512 (contiguous after a_n)
    float* sim  = v_n  + (size_t)B_DIM * V_DIM * D_DIM;      // 16 x 1024 x 512
    float* rmax = sim  + (size_t)B_DIM * A_DIM * V_DIM;      // 16384
    float* rinv = rmax + (size_t)B_DIM * A_DIM;              // 16384

    // 1) projections: X @ W^T + b
    gemm_nt_kernel<<<dim3(D_DIM/TBN, (B_DIM*A_DIM)/TBM, 1), dim3(256), 0, stream>>>(
        audio, W, bias, a_n, B_DIM*A_DIM, D_DIM, D_DIM, 0, 0, 0);
    gemm_nt_kernel<<<dim3(D_DIM/TBN, (B_DIM*V_DIM)/TBM, 1), dim3(256), 0, stream>>>(
        video, W, bias, v_n, B_DIM*V_DIM, D_DIM, D_DIM, 0, 0, 0);

    // 2) L2-normalize all 24576 projected rows (a_n and v_n are contiguous)
    rownorm_kernel<<<dim3((B_DIM*(A_DIM+V_DIM))/4), dim3(256), 0, stream>>>(a_n);

    // 3) sim[b] = a_n[b] @ v_n[b]^T   (batched NT)
    gemm_nt_kernel<<<dim3(V_DIM/TBN, A_DIM/TBM, B_DIM), dim3(256), 0, stream>>>(
        a_n, v_n, nullptr, sim, A_DIM, V_DIM, D_DIM,
        (size_t)A_DIM*D_DIM, (size_t)V_DIM*D_DIM, (size_t)A_DIM*V_DIM);

    // 4) softmax row stats
    rowstat_kernel<<<dim3((B_DIM*A_DIM)/4), dim3(256), 0, stream>>>(sim, rmax, rinv);

    // 5) aligned = softmax(sim) @ video
    gemm_pv_kernel<<<dim3(D_DIM/TBN, A_DIM/TBM, B_DIM), dim3(256), 0, stream>>>(
        sim, rmax, rinv, video, out_aligned);

    // 6) DTW alignment score (wave-scan formulation)
    dtw_scan_kernel<<<dim3(B_DIM), dim3(64), 0, stream>>>(sim, out_score);
}

// Round 3
// 780.399 us; speedup vs baseline: 1.7371x; 1.0809x over previous
//
#include <hip/hip_runtime.h>
#include <math.h>

#define B_DIM 16
#define A_DIM 1024
#define V_DIM 512
#define D_DIM 512
#define NEGV  (-1e30f)

#define TBM 128
#define TBN 128
#define TBK 16

// ---------------------------------------------------------------------------
// NT GEMM: C[M,N] = A[M,K] * B[N,K]^T (+bias), batched via element strides.
// ---------------------------------------------------------------------------
__global__ __launch_bounds__(256) void gemm_nt_kernel(
    const float* __restrict__ Ag, const float* __restrict__ Bg,
    const float* __restrict__ bias, float* __restrict__ Cg,
    int M, int N, int K, size_t sA, size_t sB, size_t sC)
{
    __shared__ __align__(16) float As[TBK][TBM + 4];
    __shared__ __align__(16) float Bs[TBK][TBN + 4];

    const float* Ab = Ag + (size_t)blockIdx.z * sA;
    const float* Bb = Bg + (size_t)blockIdx.z * sB;
    float*       Cb = Cg + (size_t)blockIdx.z * sC;

    const int m0 = blockIdx.y * TBM;
    const int n0 = blockIdx.x * TBN;
    const int tid = threadIdx.x;

    const int lr  = tid >> 2;
    const int lk4 = (tid & 3) * 4;
    const int tx = tid & 15;
    const int ty = tid >> 4;

    const float* aptr0 = Ab + (size_t)(m0 + lr)      * K + lk4;
    const float* aptr1 = Ab + (size_t)(m0 + lr + 64) * K + lk4;
    const float* bptr0 = Bb + (size_t)(n0 + lr)      * K + lk4;
    const float* bptr1 = Bb + (size_t)(n0 + lr + 64) * K + lk4;

    float acc[8][8];
    #pragma unroll
    for (int i = 0; i < 8; ++i)
        #pragma unroll
        for (int j = 0; j < 8; ++j) acc[i][j] = 0.f;

    for (int k0 = 0; k0 < K; k0 += TBK) {
        float4 a0 = *(const float4*)(aptr0 + k0);
        float4 a1 = *(const float4*)(aptr1 + k0);
        float4 b0 = *(const float4*)(bptr0 + k0);
        float4 b1 = *(const float4*)(bptr1 + k0);
        __syncthreads();
        As[lk4+0][lr]    = a0.x; As[lk4+1][lr]    = a0.y; As[lk4+2][lr]    = a0.z; As[lk4+3][lr]    = a0.w;
        As[lk4+0][lr+64] = a1.x; As[lk4+1][lr+64] = a1.y; As[lk4+2][lr+64] = a1.z; As[lk4+3][lr+64] = a1.w;
        Bs[lk4+0][lr]    = b0.x; Bs[lk4+1][lr]    = b0.y; Bs[lk4+2][lr]    = b0.z; Bs[lk4+3][lr]    = b0.w;
        Bs[lk4+0][lr+64] = b1.x; Bs[lk4+1][lr+64] = b1.y; Bs[lk4+2][lr+64] = b1.z; Bs[lk4+3][lr+64] = b1.w;
        __syncthreads();
        #pragma unroll
        for (int kk = 0; kk < TBK; ++kk) {
            float4 av0 = *(const float4*)&As[kk][ty*8];
            float4 av1 = *(const float4*)&As[kk][ty*8+4];
            float4 bv0 = *(const float4*)&Bs[kk][tx*8];
            float4 bv1 = *(const float4*)&Bs[kk][tx*8+4];
            float a[8] = {av0.x, av0.y, av0.z, av0.w, av1.x, av1.y, av1.z, av1.w};
            float b[8] = {bv0.x, bv0.y, bv0.z, bv0.w, bv1.x, bv1.y, bv1.z, bv1.w};
            #pragma unroll
            for (int i = 0; i < 8; ++i)
                #pragma unroll
                for (int j = 0; j < 8; ++j)
                    acc[i][j] = fmaf(a[i], b[j], acc[i][j]);
        }
    }

    float bv[8];
    #pragma unroll
    for (int j = 0; j < 8; ++j) bv[j] = bias ? bias[n0 + tx*8 + j] : 0.f;
    #pragma unroll
    for (int i = 0; i < 8; ++i) {
        float* crow = Cb + (size_t)(m0 + ty*8 + i) * N + n0 + tx*8;
        float4 o0 = make_float4(acc[i][0]+bv[0], acc[i][1]+bv[1], acc[i][2]+bv[2], acc[i][3]+bv[3]);
        float4 o1 = make_float4(acc[i][4]+bv[4], acc[i][5]+bv[5], acc[i][6]+bv[6], acc[i][7]+bv[7]);
        *(float4*)(crow)     = o0;
        *(float4*)(crow + 4) = o1;
    }
}

// ---------------------------------------------------------------------------
// Row L2-normalize in place. One wave/row.
// ---------------------------------------------------------------------------
__global__ __launch_bounds__(256) void rownorm_kernel(float* __restrict__ x)
{
    const int wave = threadIdx.x >> 6;
    const int lane = threadIdx.x & 63;
    const size_t r = (size_t)blockIdx.x * 4 + wave;
    float* p = x + r * D_DIM;
    float4 u = *(float4*)(p + lane*4);
    float4 w = *(float4*)(p + 256 + lane*4);
    float ss = u.x*u.x + u.y*u.y + u.z*u.z + u.w*u.w
             + w.x*w.x + w.y*w.y + w.z*w.z + w.w*w.w;
    #pragma unroll
    for (int m = 1; m < 64; m <<= 1) ss += __shfl_xor(ss, m, 64);
    const float inv = 1.0f / fmaxf(sqrtf(ss), 1e-12f);
    u.x*=inv; u.y*=inv; u.z*=inv; u.w*=inv;
    w.x*=inv; w.y*=inv; w.z*=inv; w.w*=inv;
    *(float4*)(p + lane*4)       = u;
    *(float4*)(p + 256 + lane*4) = w;
}

// ---------------------------------------------------------------------------
// Softmax row stats: rmax[r], rinv[r] = 1/sum(exp(s-max)).
// ---------------------------------------------------------------------------
__global__ __launch_bounds__(256) void rowstat_kernel(
    const float* __restrict__ sim, float* __restrict__ rmax, float* __restrict__ rinv)
{
    const int wave = threadIdx.x >> 6;
    const int lane = threadIdx.x & 63;
    const size_t r = (size_t)blockIdx.x * 4 + wave;
    const float* p = sim + r * V_DIM;
    float4 u = *(const float4*)(p + lane*4);
    float4 w = *(const float4*)(p + 256 + lane*4);
    float m = fmaxf(fmaxf(fmaxf(u.x,u.y), fmaxf(u.z,u.w)),
                    fmaxf(fmaxf(w.x,w.y), fmaxf(w.z,w.w)));
    #pragma unroll
    for (int s = 1; s < 64; s <<= 1) m = fmaxf(m, __shfl_xor(m, s, 64));
    float e = __expf(u.x-m)+__expf(u.y-m)+__expf(u.z-m)+__expf(u.w-m)
            + __expf(w.x-m)+__expf(w.y-m)+__expf(w.z-m)+__expf(w.w-m);
    #pragma unroll
    for (int s = 1; s < 64; s <<= 1) e += __shfl_xor(e, s, 64);
    if (lane == 0) { rmax[r] = m; rinv[r] = 1.0f / e; }
}

// ---------------------------------------------------------------------------
// PV GEMM (NN): out[b] = softmax(sim[b]) @ video[b].
// ---------------------------------------------------------------------------
__global__ __launch_bounds__(256) void gemm_pv_kernel(
    const float* __restrict__ sim, const float* __restrict__ rmax,
    const float* __restrict__ rinv, const float* __restrict__ video,
    float* __restrict__ out)
{
    __shared__ __align__(16) float As[TBK][TBM + 4];
    __shared__ __align__(16) float Bs[TBK][TBN + 4];

    const int b = blockIdx.z;
    const float* Sb = sim   + (size_t)b * A_DIM * V_DIM;
    const float* Vb = video + (size_t)b * V_DIM * D_DIM;
    float*       Ob = out   + (size_t)b * A_DIM * D_DIM;

    const int m0 = blockIdx.y * TBM;
    const int n0 = blockIdx.x * TBN;
    const int tid = threadIdx.x;

    const int lr  = tid >> 2;
    const int lk4 = (tid & 3) * 4;
    const int bkk = tid >> 4;
    const int bn4 = (tid & 15) * 4;
    const int tx = tid & 15;
    const int ty = tid >> 4;

    const float rm0 = rmax[(size_t)b*A_DIM + m0 + lr];
    const float ri0 = rinv[(size_t)b*A_DIM + m0 + lr];
    const float rm1 = rmax[(size_t)b*A_DIM + m0 + lr + 64];
    const float ri1 = rinv[(size_t)b*A_DIM + m0 + lr + 64];

    const float* sptr0 = Sb + (size_t)(m0 + lr)      * V_DIM + lk4;
    const float* sptr1 = Sb + (size_t)(m0 + lr + 64) * V_DIM + lk4;

    float acc[8][8];
    #pragma unroll
    for (int i = 0; i < 8; ++i)
        #pragma unroll
        for (int j = 0; j < 8; ++j) acc[i][j] = 0.f;

    const float L2E = 1.44269504f;
    for (int k0 = 0; k0 < V_DIM; k0 += TBK) {
        float4 s0 = *(const float4*)(sptr0 + k0);
        float4 s1 = *(const float4*)(sptr1 + k0);
        float4 v0 = *(const float4*)(Vb + (size_t)(k0 + bkk) * D_DIM + n0 + bn4);
        float4 v1 = *(const float4*)(Vb + (size_t)(k0 + bkk) * D_DIM + n0 + bn4 + 64);
        __syncthreads();
        As[lk4+0][lr]    = exp2f((s0.x-rm0)*L2E)*ri0;
        As[lk4+1][lr]    = exp2f((s0.y-rm0)*L2E)*ri0;
        As[lk4+2][lr]    = exp2f((s0.z-rm0)*L2E)*ri0;
        As[lk4+3][lr]    = exp2f((s0.w-rm0)*L2E)*ri0;
        As[lk4+0][lr+64] = exp2f((s1.x-rm1)*L2E)*ri1;
        As[lk4+1][lr+64] = exp2f((s1.y-rm1)*L2E)*ri1;
        As[lk4+2][lr+64] = exp2f((s1.z-rm1)*L2E)*ri1;
        As[lk4+3][lr+64] = exp2f((s1.w-rm1)*L2E)*ri1;
        *(float4*)&Bs[bkk][bn4]      = v0;
        *(float4*)&Bs[bkk][bn4+64]   = v1;
        __syncthreads();
        #pragma unroll
        for (int kk = 0; kk < TBK; ++kk) {
            float4 av0 = *(const float4*)&As[kk][ty*8];
            float4 av1 = *(const float4*)&As[kk][ty*8+4];
            float4 bv0 = *(const float4*)&Bs[kk][tx*8];
            float4 bv1 = *(const float4*)&Bs[kk][tx*8+4];
            float a[8] = {av0.x, av0.y, av0.z, av0.w, av1.x, av1.y, av1.z, av1.w};
            float bb[8] = {bv0.x, bv0.y, bv0.z, bv0.w, bv1.x, bv1.y, bv1.z, bv1.w};
            #pragma unroll
            for (int i = 0; i < 8; ++i)
                #pragma unroll
                for (int j = 0; j < 8; ++j)
                    acc[i][j] = fmaf(a[i], bb[j], acc[i][j]);
        }
    }

    #pragma unroll
    for (int i = 0; i < 8; ++i) {
        float* crow = Ob + (size_t)(m0 + ty*8 + i) * D_DIM + n0 + tx*8;
        float4 o0 = make_float4(acc[i][0], acc[i][1], acc[i][2], acc[i][3]);
        float4 o1 = make_float4(acc[i][4], acc[i][5], acc[i][6], acc[i][7]);
        *(float4*)(crow)     = o0;
        *(float4*)(crow + 4) = o1;
    }
}

// ---------------------------------------------------------------------------
// DPP helpers (wave64).
// ---------------------------------------------------------------------------
template <int CTRL, int RMASK>
__device__ __forceinline__ float fdpp(float oldv, float src) {
    int r = __builtin_amdgcn_update_dpp(
        __float_as_int(oldv), __float_as_int(src), CTRL, RMASK, 0xF, false);
    return __int_as_float(r);
}

__device__ __forceinline__ float wave_incl_add(float x) {
    x += fdpp<0x111, 0xF>(0.f, x);   // row_shr:1
    x += fdpp<0x112, 0xF>(0.f, x);   // row_shr:2
    x += fdpp<0x114, 0xF>(0.f, x);   // row_shr:4
    x += fdpp<0x118, 0xF>(0.f, x);   // row_shr:8
    x += fdpp<0x142, 0xA>(0.f, x);   // row_bcast:15 -> rows 1,3
    x += fdpp<0x143, 0xC>(0.f, x);   // row_bcast:31 -> rows 2,3
    return x;
}

__device__ __forceinline__ float wave_incl_max(float x) {
    x = fmaxf(x, fdpp<0x111, 0xF>(NEGV, x));
    x = fmaxf(x, fdpp<0x112, 0xF>(NEGV, x));
    x = fmaxf(x, fdpp<0x114, 0xF>(NEGV, x));
    x = fmaxf(x, fdpp<0x118, 0xF>(NEGV, x));
    x = fmaxf(x, fdpp<0x142, 0xA>(NEGV, x));
    x = fmaxf(x, fdpp<0x143, 0xC>(NEGV, x));
    return x;
}

// ---------------------------------------------------------------------------
// In-place inclusive prefix sum along each sim row (1 wave per row).
// Lane l owns 8 contiguous columns [8l..8l+7] — same layout dtw expects.
// ---------------------------------------------------------------------------
__global__ __launch_bounds__(256) void rowpsum_kernel(float* __restrict__ sim)
{
    const int wave = threadIdx.x >> 6;
    const int lane = threadIdx.x & 63;
    const size_t r = (size_t)blockIdx.x * 4 + wave;
    float* p = sim + r * V_DIM + lane * 8;
    float4 u = *(float4*)p;
    float4 w = *(float4*)(p + 4);
    float s[8] = {u.x,u.y,u.z,u.w,w.x,w.y,w.z,w.w};
    #pragma unroll
    for (int k = 1; k < 8; ++k) s[k] += s[k-1];
    float excl = fdpp<0x138, 0xF>(0.f, wave_incl_add(s[7]));  // wave_shr:1, lane0->0
    #pragma unroll
    for (int k = 0; k < 8; ++k) s[k] += excl;
    *(float4*)p       = make_float4(s[0], s[1], s[2], s[3]);
    *(float4*)(p + 4) = make_float4(s[4], s[5], s[6], s[7]);
}

// ---------------------------------------------------------------------------
// DTW row step on PRE-SUMMED rows. Pk[k] = inclusive prefix sum P at this
// lane's columns. dp_j = P_j + max_{k<=j}(m_k - P_{k-1}).
// Serial chain: dpp + max/sub + KS(3) + wave max(6) + shr + add ~ 14 ops.
// ---------------------------------------------------------------------------
__device__ __forceinline__ void dtw_row_p(const float Pk[8], float dp[8], float bnd)
{
    float Pexcl    = fdpp<0x138, 0xF>(0.0f, Pk[7]);   // P_{j-1} at lane's first col
    float prevlast = fdpp<0x138, 0xF>(bnd,  dp[7]);   // prev row dp at col j-1
    float q[8];
    q[0] = fmaxf(dp[0], prevlast) - Pexcl;
    #pragma unroll
    for (int k = 1; k < 8; ++k) q[k] = fmaxf(dp[k], dp[k-1]) - Pk[k-1];
    // Kogge-Stone in-lane inclusive max scan (depth 3)
    #pragma unroll
    for (int d = 1; d < 8; d <<= 1)
        #pragma unroll
        for (int k = 7; k >= d; --k) q[k] = fmaxf(q[k], q[k-d]);
    // exclusive wave max of lane maxima
    float Qexcl = fdpp<0x138, 0xF>(NEGV, wave_incl_max(q[7]));
    #pragma unroll
    for (int k = 0; k < 8; ++k) dp[k] = Pk[k] + fmaxf(Qexcl, q[k]);
}

__global__ __launch_bounds__(64) void dtw_scan_kernel(
    const float* __restrict__ psum, float* __restrict__ score)
{
    const int b = blockIdx.x;
    const int lane = threadIdx.x;
    const float* S = psum + (size_t)b * A_DIM * V_DIM + lane * 8;

    float dp[8];
    #pragma unroll
    for (int k = 0; k < 8; ++k) dp[k] = NEGV;

    // 8-row-deep register prefetch ring
    float4 pa[8], pb[8];
    #pragma unroll
    for (int u = 0; u < 8; ++u) {
        pa[u] = *(const float4*)(S + (size_t)u * V_DIM);
        pb[u] = *(const float4*)(S + (size_t)u * V_DIM + 4);
    }

    for (int i0 = 1; i0 <= A_DIM; i0 += 8) {
        #pragma unroll
        for (int u = 0; u < 8; ++u) {
            float P[8] = {pa[u].x, pa[u].y, pa[u].z, pa[u].w,
                          pb[u].x, pb[u].y, pb[u].z, pb[u].w};
            const int nr = i0 + 8 + u;            // prefetch row number (1-based)
            if (nr <= A_DIM) {
                pa[u] = *(const float4*)(S + (size_t)(nr - 1) * V_DIM);
                pb[u] = *(const float4*)(S + (size_t)(nr - 1) * V_DIM + 4);
            }
            dtw_row_p(P, dp, (i0 + u == 1) ? 0.0f : NEGV);
        }
    }
    if (lane == 63) score[b] = dp[7];   // dp[A][V]
}

// ---------------------------------------------------------------------------
extern "C" void kernel_launch(void* const* d_in, const int* in_sizes, int n_in,
                              void* d_out, int out_size, void* d_ws, size_t ws_size,
                              hipStream_t stream)
{
    const float* audio = (const float*)d_in[0];   // [16,1024,512]
    const float* video = (const float*)d_in[1];   // [16, 512,512]
    const float* W     = (const float*)d_in[2];   // [512,512]
    const float* bias  = (const float*)d_in[3];   // [512]

    float* out_aligned = (float*)d_out;                                   // [16,1024,512]
    float* out_score   = (float*)d_out + (size_t)B_DIM * A_DIM * D_DIM;   // [16]

    float* ws   = (float*)d_ws;
    float* a_n  = ws;                                        // 16384 x 512
    float* v_n  = a_n  + (size_t)B_DIM * A_DIM * D_DIM;      //  8192 x 512
    float* sim  = v_n  + (size_t)B_DIM * V_DIM * D_DIM;      // 16 x 1024 x 512
    float* rmax = sim  + (size_t)B_DIM * A_DIM * V_DIM;      // 16384
    float* rinv = rmax + (size_t)B_DIM * A_DIM;              // 16384

    // 1) projections: X @ W^T + b
    gemm_nt_kernel<<<dim3(D_DIM/TBN, (B_DIM*A_DIM)/TBM, 1), dim3(256), 0, stream>>>(
        audio, W, bias, a_n, B_DIM*A_DIM, D_DIM, D_DIM, 0, 0, 0);
    gemm_nt_kernel<<<dim3(D_DIM/TBN, (B_DIM*V_DIM)/TBM, 1), dim3(256), 0, stream>>>(
        video, W, bias, v_n, B_DIM*V_DIM, D_DIM, D_DIM, 0, 0, 0);

    // 2) L2-normalize all projected rows
    rownorm_kernel<<<dim3((B_DIM*(A_DIM+V_DIM))/4), dim3(256), 0, stream>>>(a_n);

    // 3) sim[b] = a_n[b] @ v_n[b]^T
    gemm_nt_kernel<<<dim3(V_DIM/TBN, A_DIM/TBM, B_DIM), dim3(256), 0, stream>>>(
        a_n, v_n, nullptr, sim, A_DIM, V_DIM, D_DIM,
        (size_t)A_DIM*D_DIM, (size_t)V_DIM*D_DIM, (size_t)A_DIM*V_DIM);

    // 4) softmax row stats (raw sim)
    rowstat_kernel<<<dim3((B_DIM*A_DIM)/4), dim3(256), 0, stream>>>(sim, rmax, rinv);

    // 5) aligned = softmax(sim) @ video   (raw sim)
    gemm_pv_kernel<<<dim3(D_DIM/TBN, A_DIM/TBM, B_DIM), dim3(256), 0, stream>>>(
        sim, rmax, rinv, video, out_aligned);

    // 6) in-place row prefix sums of sim (sim no longer needed raw)
    rowpsum_kernel<<<dim3((B_DIM*A_DIM)/4), dim3(256), 0, stream>>>(sim);

    // 7) DTW alignment score from pre-summed rows
    dtw_scan_kernel<<<dim3(B_DIM), dim3(64), 0, stream>>>(sim, out_score);
}